// Round 6
// baseline (868.622 us; speedup 1.0000x reference)
//
#include <hip/hip_runtime.h>
#include <cstdint>

typedef unsigned short u16;
typedef __attribute__((ext_vector_type(8))) short short8;
typedef __attribute__((ext_vector_type(4))) float floatx4;
typedef __attribute__((ext_vector_type(4))) float f4;

#define NQP   64
#define MQP   128
#define NP    2080
#define NHH   8192
#define NOUT  10464   /* 2080 + 64 + 8192 + 128 */
#define NOUTP 10496   /* padded to 82*128 */
#define HOFF  2144    /* NP + NQP */

__device__ __forceinline__ float b2f(u16 u) {
  union { unsigned int i; float f; } v; v.i = ((unsigned int)u) << 16; return v.f;
}
__device__ __forceinline__ u16 f2b(float f) {
  union { float f; unsigned int i; } v; v.f = f;
  unsigned int r = v.i + 0x7fffu + ((v.i >> 16) & 1u);
  return (u16)(r >> 16);
}

// ---------------------------------------------------------------------------
// dtype detector (flag=1 -> inputs are f32)
// ---------------------------------------------------------------------------
__global__ __launch_bounds__(256) void detect_dtype(const u16* __restrict__ w,
                                                    int* __restrict__ flag) {
  __shared__ int cnt;
  if (threadIdx.x == 0) cnt = 0;
  __syncthreads();
  int c = 0;
  for (int i = threadIdx.x; i < 16384; i += 256) {
    const int e = (w[i] >> 7) & 0xFF;
    if (e >= 130 || e <= 90) ++c;
  }
  atomicAdd(&cnt, c);
  __syncthreads();
  if (threadIdx.x == 0) flag[0] = (cnt > 3000) ? 1 : 0;
}

__device__ __forceinline__ u16 load_elem_bf16(const void* p, size_t idx, int isf32) {
  return isf32 ? f2b(((const float*)p)[idx]) : ((const u16*)p)[idx];
}

__global__ __launch_bounds__(256) void convert_bf16(const void* __restrict__ in,
                                                    u16* __restrict__ out, int n,
                                                    const int* __restrict__ flag) {
  const int isf = flag[0];
  for (int i = blockIdx.x * 256 + threadIdx.x; i < n; i += gridDim.x * 256)
    out[i] = load_elem_bf16(in, i, isf);
}

// all three biases in one launch
__global__ __launch_bounds__(256) void conv_biases(const void* __restrict__ b1,
                                                   const void* __restrict__ b2,
                                                   const void* __restrict__ b3,
                                                   float* __restrict__ bf1,
                                                   float* __restrict__ bf2,
                                                   float* __restrict__ bf3,
                                                   const int* __restrict__ flag) {
  const int isf = flag[0];
  const int i = blockIdx.x * 256 + threadIdx.x;
  if (i < 1024) {
    bf1[i] = isf ? ((const float*)b1)[i] : b2f(((const u16*)b1)[i]);
  } else if (i < 2048) {
    const int j = i - 1024;
    bf2[j] = isf ? ((const float*)b2)[j] : b2f(((const u16*)b2)[j]);
  } else if (i < 2048 + NOUT) {
    const int j = i - 2048;
    bf3[j] = isf ? ((const float*)b3)[j] : b2f(((const u16*)b3)[j]);
  }
}

// ---------------------------------------------------------------------------
// All three weight transposes in one launch.
// ---------------------------------------------------------------------------
__global__ __launch_bounds__(256) void transpose_all(const void* __restrict__ W1,
                                                     const void* __restrict__ W2,
                                                     const void* __restrict__ W3,
                                                     u16* __restrict__ W1t,
                                                     u16* __restrict__ W2t,
                                                     u16* __restrict__ W3t,
                                                     const int* __restrict__ flag) {
  const int bx = blockIdx.x, by = blockIdx.y;
  const void* in; u16* out; int K, N, Npad, bxo;
  if (bx < 32)      { in = W1; out = W1t; K = 512;  N = 1024; Npad = 1024;  bxo = 0;
                      if (by >= 16) return; }
  else if (bx < 64) { in = W2; out = W2t; K = 1024; N = 1024; Npad = 1024;  bxo = 32; }
  else              { in = W3; out = W3t; K = 1024; N = NOUT; Npad = NOUTP; bxo = 64; }
  __shared__ u16 tile[32][33];
  const int isf = flag[0];
  const int n0 = (bx - bxo) * 32, k0 = by * 32;
  const int tx = threadIdx.x & 31, ty = threadIdx.x >> 5;
#pragma unroll
  for (int i = 0; i < 4; ++i) {
    const int k = k0 + ty + 8 * i, n = n0 + tx;
    tile[ty + 8 * i][tx] = (n < N) ? load_elem_bf16(in, (size_t)k * N + n, isf) : (u16)0;
  }
  __syncthreads();
#pragma unroll
  for (int i = 0; i < 4; ++i) {
    const int n = n0 + ty + 8 * i, k = k0 + tx;
    if (n < Npad) out[(size_t)n * K + k] = tile[tx][ty + 8 * i];
  }
}

// ---------------------------------------------------------------------------
// GEMM (m97-style 128x128 tile), unchanged.
// ---------------------------------------------------------------------------
__device__ __forceinline__ void gload_lds16(const u16* g, u16* l) {
  __builtin_amdgcn_global_load_lds((const __attribute__((address_space(1))) void*)g,
                                   (__attribute__((address_space(3))) void*)l, 16, 0, 0);
}

template <int EPI, bool HAS_LO>
__global__ __launch_bounds__(256) void gemm_bt(const u16* __restrict__ Ahi, const u16* __restrict__ Alo,
                                               const u16* __restrict__ Bt,  const float* __restrict__ bias,
                                               u16* __restrict__ Chi, u16* __restrict__ Clo,
                                               float* __restrict__ Cf,
                                               int M, int N, int K) {
  __shared__ __align__(16) u16 lA[128 * 32];
  __shared__ __align__(16) u16 lAlo[128 * 32];
  __shared__ __align__(16) u16 lB[128 * 32];
  const int tile_n = blockIdx.x * 128;
  const int tile_m = blockIdx.y * 128;
  const int lane = threadIdx.x & 63;
  const int wv   = threadIdx.x >> 6;
  const int wm = (wv & 1) * 64;
  const int wn = (wv >> 1) * 64;
  const int sr = lane >> 2;
  const int sk = (lane & 3) * 8;
  floatx4 acc[4][4] = {};

  for (int k0 = 0; k0 < K; k0 += 32) {
#pragma unroll
    for (int it = 0; it < 2; ++it) {
      const int slot = it * 4 + wv;
      const int r = slot * 16 + sr;
      gload_lds16(Ahi + (size_t)(tile_m + r) * K + k0 + sk, lA + slot * 512);
      if (HAS_LO)
        gload_lds16(Alo + (size_t)(tile_m + r) * K + k0 + sk, lAlo + slot * 512);
      gload_lds16(Bt + (size_t)(tile_n + r) * K + k0 + sk, lB + slot * 512);
    }
    __syncthreads();
    const int ro = lane & 15;
    const int qo = (lane >> 4) * 8;
    short8 af[4], bfr[4], al[4];
#pragma unroll
    for (int i = 0; i < 4; ++i) af[i] = *(const short8*)(lA + (wm + i * 16 + ro) * 32 + qo);
#pragma unroll
    for (int j = 0; j < 4; ++j) bfr[j] = *(const short8*)(lB + (wn + j * 16 + ro) * 32 + qo);
    if (HAS_LO) {
#pragma unroll
      for (int i = 0; i < 4; ++i) al[i] = *(const short8*)(lAlo + (wm + i * 16 + ro) * 32 + qo);
    }
#pragma unroll
    for (int i = 0; i < 4; ++i)
#pragma unroll
      for (int j = 0; j < 4; ++j) {
        acc[i][j] = __builtin_amdgcn_mfma_f32_16x16x32_bf16(af[i], bfr[j], acc[i][j], 0, 0, 0);
        if (HAS_LO)
          acc[i][j] = __builtin_amdgcn_mfma_f32_16x16x32_bf16(al[i], bfr[j], acc[i][j], 0, 0, 0);
      }
    __syncthreads();
  }

  const int colb = tile_n + wn + (lane & 15);
  const int rowb = tile_m + wm + (lane >> 4) * 4;
#pragma unroll
  for (int j = 0; j < 4; ++j) {
    const int col = colb + j * 16;
    const float bv = (col < N) ? bias[col] : 0.f;
#pragma unroll
    for (int i = 0; i < 4; ++i) {
#pragma unroll
      for (int v = 0; v < 4; ++v) {
        const int row = rowb + i * 16 + v;
        float val = acc[i][j][v] + bv;
        if (EPI == 0) {
          val = fmaxf(val, 0.f);
          const u16 hi = f2b(val);
          const float lo = val - b2f(hi);
          Chi[(size_t)row * N + col] = hi;
          Clo[(size_t)row * N + col] = f2b(lo);
        } else {
          if (col < N) Cf[(size_t)row * N + col] = val;
        }
      }
    }
  }
}

// ---------------------------------------------------------------------------
// QP helpers
// ---------------------------------------------------------------------------
__device__ __forceinline__ f4 ld4s(const float* p) { return *(const f4*)p; }
__device__ __forceinline__ void st4s(float* p, f4 v) { *(f4*)p = v; }
__device__ __forceinline__ float dot4(f4 a, f4 b) {
  return fmaf(a.x, b.x, fmaf(a.y, b.y, fmaf(a.z, b.z, a.w * b.w)));
}

// ---------------------------------------------------------------------------
// Per-batch QP solver: ONE WAVE per batch element (64-thread blocks).
// H rows (l, l+64) + H^T column l + Minv row l all in REGISTERS (~350 VGPR,
// 1 wave/SIMD). All PDHG-loop LDS reads are uniform-address broadcasts
// (conflict-free). No cross-wave synchronization exists at all.
// ---------------------------------------------------------------------------
__global__ __launch_bounds__(64, 1) void qp_solve(const float* __restrict__ outbuf,
                                                  void* __restrict__ xs,
                                                  const int* __restrict__ flag) {
  __shared__ __align__(16) float Ld[64 * 68];   // dense zero-padded L (setup only)
  __shared__ __align__(16) float vec_s[64];     // v / xbar
  __shared__ __align__(16) float lam_sh[128];   // lam / power-iter w
  __shared__ __align__(16) float rhs_sh[64];    // rhs / GJ pivot row
  __shared__ __align__(16) float q_sh[64];

  const int l = threadIdx.x;                    // 0..63
  const int isf = flag[0];
  const float* ob = outbuf + (size_t)blockIdx.x * NOUT;

  // ---- build dense L ----
  for (int e = l; e < 64 * 68; e += 64) Ld[e] = 0.f;
  q_sh[l] = ob[NP + l];
  __syncthreads();
  for (int e = l; e < NP; e += 64) {
    int i = (int)((sqrtf(8.f * (float)e + 1.f) - 1.f) * 0.5f);
    while ((i + 1) * (i + 2) / 2 <= e) ++i;
    while (i * (i + 1) / 2 > e) --i;
    const int j = e - i * (i + 1) / 2;   // j <= i
    Ld[i * 68 + j] = ob[e];
  }
  __syncthreads();
  {
    const float xv = Ld[l * 68 + l];
    Ld[l * 68 + l] = 0.1f + (fmaxf(xv, 0.f) + log1pf(expf(-fabsf(xv))));
  }
  __syncthreads();

  // ---- P = L L^T, row l into registers (j unrolled -> constant indexing) ----
  f4 Mrow[16];
  {
    f4 Lr[17];
#pragma unroll
    for (int g = 0; g < 17; ++g) Lr[g] = ld4s(&Ld[l * 68 + 4 * g]);
#pragma unroll
    for (int j = 0; j < 64; ++j) {
      float s = 0.f;
#pragma unroll
      for (int g = 0; g <= (j >> 2); ++g) s += dot4(Lr[g], ld4s(&Ld[j * 68 + 4 * g]));
      Mrow[j >> 2][j & 3] = s;
    }
  }
  __syncthreads();

  // ---- H into registers straight from global ----
  f4 R0[16], R1[16], HT[32];
#pragma unroll
  for (int g = 0; g < 16; ++g) R0[g] = *(const f4*)(ob + HOFF + l * 64 + 4 * g);
#pragma unroll
  for (int g = 0; g < 16; ++g) R1[g] = *(const f4*)(ob + HOFF + (l + 64) * 64 + 4 * g);
#pragma unroll
  for (int mg = 0; mg < 32; ++mg) {
    f4 h;
    h.x = ob[HOFF + (4 * mg + 0) * 64 + l];
    h.y = ob[HOFF + (4 * mg + 1) * 64 + l];
    h.z = ob[HOFF + (4 * mg + 2) * 64 + l];
    h.w = ob[HOFF + (4 * mg + 3) * 64 + l];
    HT[mg] = h;
  }
  const float b0 = ob[HOFF + NHH + l];
  const float b1 = ob[HOFF + NHH + 64 + l];

  // ---- power iteration (10) ----
  vec_s[l] = 0.125f;
  __syncthreads();
  for (int pi = 0; pi < 10; ++pi) {
    float s0 = 0.f, s1 = 0.f;
#pragma unroll
    for (int g = 0; g < 16; ++g) {
      const f4 xv = ld4s(&vec_s[4 * g]);
      s0 += dot4(R0[g], xv); s1 += dot4(R1[g], xv);
    }
    lam_sh[l] = s0; lam_sh[l + 64] = s1;
    __syncthreads();
    float u = 0.f;
#pragma unroll
    for (int mg = 0; mg < 32; ++mg) u += dot4(HT[mg], ld4s(&lam_sh[4 * mg]));
    float ss = u * u;
#pragma unroll
    for (int o = 1; o <= 32; o <<= 1) ss += __shfl_xor(ss, o, 64);
    vec_s[l] = u / (sqrtf(ss) + 1e-12f);
    __syncthreads();
  }
  // ---- tau ----
  float tau;
  {
    float s0 = 0.f, s1 = 0.f;
#pragma unroll
    for (int g = 0; g < 16; ++g) {
      const f4 xv = ld4s(&vec_s[4 * g]);
      s0 += dot4(R0[g], xv); s1 += dot4(R1[g], xv);
    }
    float ss = s0 * s0 + s1 * s1;
#pragma unroll
    for (int o = 1; o <= 32; o <<= 1) ss += __shfl_xor(ss, o, 64);
    tau = 0.9f / (sqrtf(ss) + 1e-6f);
  }

  // ---- M = I + tau*P (registers, diag via compile-time-index selects) ----
#pragma unroll
  for (int jg = 0; jg < 16; ++jg) {
    f4 m = Mrow[jg] * tau;
    m.x += (4 * jg + 0 == l) ? 1.f : 0.f;
    m.y += (4 * jg + 1 == l) ? 1.f : 0.f;
    m.z += (4 * jg + 2 == l) ? 1.f : 0.f;
    m.w += (4 * jg + 3 == l) ? 1.f : 0.f;
    Mrow[jg] = m;
  }

  // ---- Gauss-Jordan in registers (SPD, no pivoting; k fully unrolled) ----
#pragma unroll
  for (int k = 0; k < 64; ++k) {
    if (l == k) {
#pragma unroll
      for (int jg = 0; jg < 16; ++jg) st4s(&rhs_sh[4 * jg], Mrow[jg]);
    }
    __syncthreads();
    const float d = 1.0f / rhs_sh[k];
    float f;
    { const f4 mk = Mrow[k >> 2];
      f = (k & 3) == 0 ? mk.x : (k & 3) == 1 ? mk.y : (k & 3) == 2 ? mk.z : mk.w; }
    const bool piv = (l == k);
#pragma unroll
    for (int jg = 0; jg < 16; ++jg) {
      const f4 srk = ld4s(&rhs_sh[4 * jg]) * d;
      const f4 m = Mrow[jg];
      f4 r;
      r.x = piv ? srk.x : fmaf(-f, srk.x, m.x);
      r.y = piv ? srk.y : fmaf(-f, srk.y, m.y);
      r.z = piv ? srk.z : fmaf(-f, srk.z, m.z);
      r.w = piv ? srk.w : fmaf(-f, srk.w, m.w);
      Mrow[jg] = r;
    }
    { const float v = piv ? d : -f * d;
      f4 mk = Mrow[k >> 2];
      if ((k & 3) == 0) mk.x = v; else if ((k & 3) == 1) mk.y = v;
      else if ((k & 3) == 2) mk.z = v; else mk.w = v;
      Mrow[k >> 2] = mk; }
    __syncthreads();
  }

  // ---- c0 = tau * (Minv q)_l ----
  float c0;
  {
    float a = 0.f;
#pragma unroll
    for (int kg = 0; kg < 16; ++kg) a += dot4(Mrow[kg], ld4s(&q_sh[4 * kg]));
    c0 = tau * a;
  }

  // ---- PDHG (50 iterations), wave-synchronous ----
  float lam0 = 0.f, lam1 = 0.f, xp = 0.f;
  vec_s[l] = 0.f;
  __syncthreads();
  for (int it = 0; it < 50; ++it) {
    float s0 = 0.f, s1 = 0.f;
#pragma unroll
    for (int g = 0; g < 16; ++g) {
      const f4 xv = ld4s(&vec_s[4 * g]);
      s0 += dot4(R0[g], xv); s1 += dot4(R1[g], xv);
    }
    lam0 = fmaxf(lam0 - tau * (s0 + b0), 0.f);
    lam1 = fmaxf(lam1 - tau * (s1 + b1), 0.f);
    lam_sh[l] = lam0; lam_sh[l + 64] = lam1;
    __syncthreads();
    float u = 0.f;
#pragma unroll
    for (int mg = 0; mg < 32; ++mg) u += dot4(HT[mg], ld4s(&lam_sh[4 * mg]));
    rhs_sh[l] = xp + tau * u;
    __syncthreads();
    float xn = 0.f;
#pragma unroll
    for (int kg = 0; kg < 16; ++kg) xn += dot4(Mrow[kg], ld4s(&rhs_sh[4 * kg]));
    xn -= c0;
    __syncthreads();
    vec_s[l] = 2.f * xn - xp;
    xp = xn;
    __syncthreads();
  }

  const size_t oi = (size_t)blockIdx.x * NQP + l;
  if (isf) ((float*)xs)[oi] = xp;
  else     ((u16*)xs)[oi]   = f2b(xp);
}

// ---------------------------------------------------------------------------
extern "C" void kernel_launch(void* const* d_in, const int* in_sizes, int n_in,
                              void* d_out, int out_size, void* d_ws, size_t ws_size,
                              hipStream_t stream) {
  const void* x  = d_in[0];
  const void* W1 = d_in[1];
  const void* b1 = d_in[2];
  const void* W2 = d_in[3];
  const void* b2 = d_in[4];
  const void* W3 = d_in[5];
  const void* b3 = d_in[6];

  char* ws = (char*)d_ws;
  size_t off = 0;
  auto take = [&](size_t bytes) -> char* {
    char* r = ws + off;
    off += (bytes + 255) & ~(size_t)255;
    return r;
  };
  int*   flag = (int*)take(256);
  float* bf1  = (float*)take(1024 * 4);
  float* bf2  = (float*)take(1024 * 4);
  float* bf3  = (float*)take((size_t)NOUT * 4);
  u16*   W3t  = (u16*)take((size_t)NOUTP * 1024 * 2);
  u16*   h2hi = (u16*)take(1024ull * 1024 * 2);
  u16*   h2lo = (u16*)take(1024ull * 1024 * 2);
  char*  region = take(1024ull * NOUT * 4);   // outf, overlaid below
  float* outf = (float*)region;
  u16* xb   = (u16*)(region + 0);                 // 1 MB
  u16* W1t  = (u16*)(region + (1u << 20));        // 1 MB
  u16* W2t  = (u16*)(region + (2u << 20));        // 2 MB
  u16* h1hi = (u16*)(region + (4u << 20));        // 2 MB
  u16* h1lo = (u16*)(region + (6u << 20));        // 2 MB
  (void)ws_size; (void)in_sizes; (void)n_in; (void)out_size;

  detect_dtype<<<dim3(1), 256, 0, stream>>>((const u16*)W1, flag);

  convert_bf16<<<dim3(512), 256, 0, stream>>>(x, xb, 1024 * 512, flag);
  conv_biases<<<dim3(49), 256, 0, stream>>>(b1, b2, b3, bf1, bf2, bf3, flag);
  transpose_all<<<dim3(392, 32), 256, 0, stream>>>(W1, W2, W3, W1t, W2t, W3t, flag);

  gemm_bt<0, false><<<dim3(8, 8), 256, 0, stream>>>(xb, nullptr, W1t, bf1,
                                                    h1hi, h1lo, nullptr, 1024, 1024, 512);
  gemm_bt<0, true><<<dim3(8, 8), 256, 0, stream>>>(h1hi, h1lo, W2t, bf2,
                                                   h2hi, h2lo, nullptr, 1024, 1024, 1024);
  gemm_bt<1, true><<<dim3(NOUTP / 128, 8), 256, 0, stream>>>(h2hi, h2lo, W3t, bf3,
                                                             nullptr, nullptr, outf, 1024, NOUT, 1024);
  qp_solve<<<dim3(1024), 64, 0, stream>>>(outf, d_out, flag);
}